// Round 5
// baseline (246.464 us; speedup 1.0000x reference)
//
#include <hip/hip_runtime.h>

// EndPointSpline: Q=2048 queries, B=128 batch cols, T=128 knot times, D=512 feat
// out[b,q,d] = xt[left,b,d] + (xt[left+1,b,d]-xt[left,b,d]) * (qt - t[left,b]) / (t[left+1,b]-t[left,b]+1e-10)
// left = clip(searchsorted(t[1:,b], qt, 'left'), 0, T-2)
// xt[0]=x0[b], xt[i]=knots[b,i-1], xt[T-1]=x1[b]
//
// R1: 16q x 16 lanes, 8 f4 iters                  -> 112.8us
// R2: + XCD-aware mapping (all q of a b on 1 XCD) -> 99.6us
// R3: 32q x 8 lanes, 16 f4 iters (2x search amort)-> 98.2us (neutral: BW-bound)
// R4: 32B/lane chunks: 8 iters x (4 loads batched -> 2 stores). Tests
//     VMEM-issue/ILP. If neutral, we're at the mixed-stream HBM ceiling.

#define QN 2048
#define BN 128
#define TN 128
#define DN 512

#define QPB 32   // queries per block
#define LPQ 8    // lanes per query, 32B (8 floats) each
#define DITER (DN / (LPQ * 8))   // 8 d-iterations

typedef float f4 __attribute__((ext_vector_type(4)));

__global__ __launch_bounds__(256) void EndPointSpline_kernel(
    const float* __restrict__ query_t,   // [Q]
    const float* __restrict__ knots,     // [B, T-2, D]
    const float* __restrict__ x0,        // [B, D]
    const float* __restrict__ x1,        // [B, D]
    const float* __restrict__ t,         // [T, B]
    float* __restrict__ out)             // [B, Q, D]
{
    // XCD-aware decode: dispatch round-robins bid%8 across the 8 XCDs.
    // Per XCD: 1024 slots = 16 b-slabs x 64 qchunks (qchunk fastest).
    const int bid    = blockIdx.x;
    const int xcd    = bid & 7;
    const int slot   = bid >> 3;                 // 0..1023 within this XCD
    const int b      = xcd + ((slot >> 6) << 3); // 16 b's per XCD
    const int qchunk = slot & 63;                // varies fastest

    const int tq   = threadIdx.x >> 3;          // 0..31 : which query in block
    const int lane = threadIdx.x & 7;           // 0..7  : 32B slot within row
    const int q    = qchunk * QPB + tq;

    const float qt = query_t[q];

    // smallest i in [0,127) with t[i+1] >= qt (127 if none) == searchsorted(t[1:], qt)
    int lo = 0, hi = TN - 1;
    while (lo < hi) {
        const int mid = (lo + hi) >> 1;
        const float tm = t[(mid + 1) * BN + b];
        if (tm < qt) lo = mid + 1; else hi = mid;
    }
    const int left = (lo > TN - 2) ? (TN - 2) : lo;   // clip to [0, T-2]

    const float tl = t[left * BN + b];
    const float tr = t[(left + 1) * BN + b];
    const float scale = (qt - tl) / (tr - tl + 1e-10f);

    const float* row0 = (left == 0)
        ? (x0 + (size_t)b * DN)
        : (knots + ((size_t)b * (TN - 2) + (left - 1)) * DN);
    const float* row1 = (left == TN - 2)
        ? (x1 + (size_t)b * DN)
        : (knots + ((size_t)b * (TN - 2) + left) * DN);

    float* orow = out + ((size_t)b * QN + q) * DN;

    const int d0 = lane << 3;                   // 0..56 step 8
#pragma unroll
    for (int di = 0; di < DITER; ++di) {
        const int d = d0 + di * (LPQ * 8);      // stride 64 floats
        // batch the 4 loads, then compute, then 2 stores
        const f4 a0 = *(const f4*)(row0 + d);
        const f4 a1 = *(const f4*)(row0 + d + 4);
        const f4 c0 = *(const f4*)(row1 + d);
        const f4 c1 = *(const f4*)(row1 + d + 4);
        f4 r0, r1;
        r0.x = fmaf(c0.x - a0.x, scale, a0.x);
        r0.y = fmaf(c0.y - a0.y, scale, a0.y);
        r0.z = fmaf(c0.z - a0.z, scale, a0.z);
        r0.w = fmaf(c0.w - a0.w, scale, a0.w);
        r1.x = fmaf(c1.x - a1.x, scale, a1.x);
        r1.y = fmaf(c1.y - a1.y, scale, a1.y);
        r1.z = fmaf(c1.z - a1.z, scale, a1.z);
        r1.w = fmaf(c1.w - a1.w, scale, a1.w);
        __builtin_nontemporal_store(r0, (f4*)(orow + d));
        __builtin_nontemporal_store(r1, (f4*)(orow + d + 4));
    }
}

extern "C" void kernel_launch(void* const* d_in, const int* in_sizes, int n_in,
                              void* d_out, int out_size, void* d_ws, size_t ws_size,
                              hipStream_t stream) {
    const float* query_t = (const float*)d_in[0];
    const float* knots   = (const float*)d_in[1];
    const float* x0      = (const float*)d_in[2];
    const float* x1      = (const float*)d_in[3];
    const float* t       = (const float*)d_in[4];
    float* out           = (float*)d_out;

    dim3 grid((QN / QPB) * BN);   // 8192 blocks, 1D, XCD-decoded in-kernel
    dim3 block(QPB * LPQ);
    EndPointSpline_kernel<<<grid, block, 0, stream>>>(query_t, knots, x0, x1, t, out);
}

// Round 6
// 97.447 us; speedup vs baseline: 2.5292x; 2.5292x over previous
//
#include <hip/hip_runtime.h>

// EndPointSpline: Q=2048 queries, B=128 batch cols, T=128 knot times, D=512 feat
// out[b,q,d] = xt[left,b,d] + (xt[left+1,b,d]-xt[left,b,d]) * (qt - t[left,b]) / (t[left+1,b]-t[left,b]+1e-10)
// left = clip(searchsorted(t[1:,b], qt, 'left'), 0, T-2)
// xt[0]=x0[b], xt[i]=knots[b,i-1], xt[T-1]=x1[b]
//
// R1: 16q x 16 lanes, 8 f4 iters                  -> 112.8us
// R2: + XCD-aware mapping (all q of a b on 1 XCD) -> 99.6us
// R3: 32q x 8 lanes, 16 f4 iters (2x search amort)-> 98.2us (neutral: BW-bound)
// R4: 32B/lane chunks                              -> 246us REGRESSION: lanes
//     wrote 16B at 32B stride -> non-contiguous store instructions -> RMW.
//     Invariant learned: every store instruction must cover a contiguous,
//     fully-written segment across lanes.
// R5: revert to R3 layout (16B/lane contiguous) + CORRECT ILP test: unroll
//     2 iters, batch the 4 loads ahead of the 2 stores, contiguity preserved.

#define QN 2048
#define BN 128
#define TN 128
#define DN 512

#define QPB 32   // queries per block
#define LPQ 8    // lanes per query, 16B (f4) each -> 128B contiguous/segment
#define DITER (DN / (LPQ * 4))   // 16 d-iterations, f4 each

typedef float f4 __attribute__((ext_vector_type(4)));

__global__ __launch_bounds__(256) void EndPointSpline_kernel(
    const float* __restrict__ query_t,   // [Q]
    const float* __restrict__ knots,     // [B, T-2, D]
    const float* __restrict__ x0,        // [B, D]
    const float* __restrict__ x1,        // [B, D]
    const float* __restrict__ t,         // [T, B]
    float* __restrict__ out)             // [B, Q, D]
{
    // XCD-aware decode: dispatch round-robins bid%8 across the 8 XCDs.
    // Per XCD: 1024 slots = 16 b-slabs x 64 qchunks (qchunk fastest).
    const int bid    = blockIdx.x;
    const int xcd    = bid & 7;
    const int slot   = bid >> 3;                 // 0..1023 within this XCD
    const int b      = xcd + ((slot >> 6) << 3); // 16 b's per XCD
    const int qchunk = slot & 63;                // varies fastest

    const int tq   = threadIdx.x >> 3;          // 0..31 : which query in block
    const int lane = threadIdx.x & 7;           // 0..7  : f4 slot within row
    const int q    = qchunk * QPB + tq;

    const float qt = query_t[q];

    // smallest i in [0,127) with t[i+1] >= qt (127 if none) == searchsorted(t[1:], qt)
    int lo = 0, hi = TN - 1;
    while (lo < hi) {
        const int mid = (lo + hi) >> 1;
        const float tm = t[(mid + 1) * BN + b];
        if (tm < qt) lo = mid + 1; else hi = mid;
    }
    const int left = (lo > TN - 2) ? (TN - 2) : lo;   // clip to [0, T-2]

    const float tl = t[left * BN + b];
    const float tr = t[(left + 1) * BN + b];
    const float scale = (qt - tl) / (tr - tl + 1e-10f);

    const float* row0 = (left == 0)
        ? (x0 + (size_t)b * DN)
        : (knots + ((size_t)b * (TN - 2) + (left - 1)) * DN);
    const float* row1 = (left == TN - 2)
        ? (x1 + (size_t)b * DN)
        : (knots + ((size_t)b * (TN - 2) + left) * DN);

    float* orow = out + ((size_t)b * QN + q) * DN;

    const int d0 = lane << 2;                   // 0..28 step 4 (16B/lane, contiguous)
#pragma unroll
    for (int di = 0; di < DITER; di += 2) {
        const int dA = d0 + di * (LPQ * 4);          // stride 32 floats
        const int dB = dA + (LPQ * 4);
        // batch all 4 loads before the 2 stores (ILP), contiguity preserved
        const f4 a0 = *(const f4*)(row0 + dA);
        const f4 c0 = *(const f4*)(row1 + dA);
        const f4 a1 = *(const f4*)(row0 + dB);
        const f4 c1 = *(const f4*)(row1 + dB);
        f4 r0, r1;
        r0.x = fmaf(c0.x - a0.x, scale, a0.x);
        r0.y = fmaf(c0.y - a0.y, scale, a0.y);
        r0.z = fmaf(c0.z - a0.z, scale, a0.z);
        r0.w = fmaf(c0.w - a0.w, scale, a0.w);
        r1.x = fmaf(c1.x - a1.x, scale, a1.x);
        r1.y = fmaf(c1.y - a1.y, scale, a1.y);
        r1.z = fmaf(c1.z - a1.z, scale, a1.z);
        r1.w = fmaf(c1.w - a1.w, scale, a1.w);
        __builtin_nontemporal_store(r0, (f4*)(orow + dA));
        __builtin_nontemporal_store(r1, (f4*)(orow + dB));
    }
}

extern "C" void kernel_launch(void* const* d_in, const int* in_sizes, int n_in,
                              void* d_out, int out_size, void* d_ws, size_t ws_size,
                              hipStream_t stream) {
    const float* query_t = (const float*)d_in[0];
    const float* knots   = (const float*)d_in[1];
    const float* x0      = (const float*)d_in[2];
    const float* x1      = (const float*)d_in[3];
    const float* t       = (const float*)d_in[4];
    float* out           = (float*)d_out;

    dim3 grid((QN / QPB) * BN);   // 8192 blocks, 1D, XCD-decoded in-kernel
    dim3 block(QPB * LPQ);
    EndPointSpline_kernel<<<grid, block, 0, stream>>>(query_t, knots, x0, x1, t, out);
}